// Round 7
// baseline (361.441 us; speedup 1.0000x reference)
//
#include <hip/hip_runtime.h>

#define EPS 1e-5f

// B=32, C=256, CC=64, template 14x14, search 64x64, K=7, 32 groups (2ch/group)

typedef __attribute__((ext_vector_type(8))) short short8;
typedef __attribute__((ext_vector_type(4))) float floatx4;

__device__ __forceinline__ unsigned short f2bf(float x) {
    union { float f; unsigned u; } v; v.f = x;
    unsigned r = v.u + 0x7FFFu + ((v.u >> 16) & 1u);   // RNE
    return (unsigned short)(r >> 16);
}
__device__ __forceinline__ float bf2f(unsigned short h) {
    union { unsigned u; float f; } v; v.u = ((unsigned)h) << 16;
    return v.f;
}

// ---------------- K1: template path (LDS-staged, grid 128 = b x oc-quarter) ----------------
__global__ __launch_bounds__(256) void k1_template(
    const float* __restrict__ tmpl, const float* __restrict__ w_t,
    const float* __restrict__ gnw, const float* __restrict__ gnb,
    float* __restrict__ t_global, float* __restrict__ t_kernel)
{
    int b = blockIdx.x >> 2, h = blockIdx.x & 3;
    int tid = threadIdx.x;
    __shared__ float Xs[32][200];
    __shared__ float T[16][200];
    __shared__ float sums[16], sumsq[16], A[16], Bb[16];
    float acc[16];
    #pragma unroll
    for (int o = 0; o < 16; ++o) acc[o] = 0.f;
    const float* wb = w_t + (h * 16) * 256;
    const float* tb = tmpl + b * 50176;
    int p = tid;
    for (int chunk = 0; chunk < 8; ++chunk) {
        __syncthreads();
        #pragma unroll
        for (int j = 0; j < 7; ++j) {
            int f4 = tid + (j << 8);
            if (f4 < 1568) {
                int ic = f4 / 49, px4 = (f4 - ic * 49) << 2;
                float4 v = *(const float4*)(tb + (chunk * 32 + ic) * 196 + px4);
                *(float4*)&Xs[ic][px4] = v;
            }
        }
        __syncthreads();
        if (p < 196) {
            for (int cc = 0; cc < 32; ++cc) {
                float xv = Xs[cc][p];
                #pragma unroll
                for (int o = 0; o < 16; ++o)
                    acc[o] += xv * wb[o * 256 + chunk * 32 + cc];
            }
        }
    }
    __syncthreads();
    if (p < 196) {
        #pragma unroll
        for (int o = 0; o < 16; ++o) T[o][p] = acc[o];
    }
    __syncthreads();
    if (tid < 16) {
        float s = 0.f, s2 = 0.f;
        for (int q = 0; q < 196; ++q) { float v = T[tid][q]; s += v; s2 += v * v; }
        sums[tid] = s; sumsq[tid] = s2;
    }
    __syncthreads();
    if (tid < 8) {
        float S  = sums[2 * tid] + sums[2 * tid + 1];
        float S2 = sumsq[2 * tid] + sumsq[2 * tid + 1];
        float mean = S * (1.f / 392.f);
        float var  = S2 * (1.f / 392.f) - mean * mean;
        float inv  = rsqrtf(var + EPS);
        for (int e = 0; e < 2; ++e) {
            int c = 2 * tid + e, gc = h * 16 + c;
            float a = gnw[gc] * inv;
            A[c] = a; Bb[c] = gnb[gc] - mean * a;
        }
    }
    __syncthreads();
    if (p < 196) {
        #pragma unroll
        for (int o = 0; o < 16; ++o) {
            float v = A[o] * T[o][p] + Bb[o];
            T[o][p] = v > 0.f ? v : 0.f;
        }
    }
    __syncthreads();
    if (tid < 16) {
        int c = tid, gc = h * 16 + c;
        float s = 0.f;
        for (int q = 0; q < 196; ++q) s += T[c][q];
        t_global[b * 64 + gc] = s * (1.f / 196.f);
        for (int t = 0; t < 49; ++t) {
            int ky = t / 7, kx = t - 7 * ky;
            float v = T[c][(2 * ky) * 14 + 2 * kx]     + T[c][(2 * ky) * 14 + 2 * kx + 1]
                    + T[c][(2 * ky + 1) * 14 + 2 * kx] + T[c][(2 * ky + 1) * 14 + 2 * kx + 1];
            t_kernel[(b * 64 + gc) * 49 + t] = v * 0.25f;
        }
    }
}

// ---------------- K_W2: prepack w_s fp32 -> bf16 ----------------
__global__ __launch_bounds__(256) void k_w2(
    const float* __restrict__ w, unsigned short* __restrict__ wsb)
{
    int i = blockIdx.x * 256 + threadIdx.x;
    if (i < 16384) wsb[i] = f2bf(w[i]);
}

// ---------------- K_W: prepack w_p1 -> bf16, K tap-major chunks of 32 ----------------
__global__ __launch_bounds__(256) void k_w(
    const float* __restrict__ w1, unsigned short* __restrict__ wpk)
{
    int i = blockIdx.x * 256 + threadIdx.x;
    if (i >= 36864) return;
    int c = i >> 11;
    int rem = i & 2047;
    int oc = rem >> 5;
    int k = rem & 31;
    int tap = c >> 1;
    int ic = ((c & 1) << 5) + k;
    wpk[i] = f2bf(w1[oc * 576 + ic * 9 + tap]);
}

// ---------------- K2: search conv1x1 via bf16 MFMA -> s NHWC fp32 + GN partials ----------------
__global__ __launch_bounds__(256) void k2_mfma(
    const float* __restrict__ x, const unsigned short* __restrict__ wsb,
    float* __restrict__ s_nhwc, float* __restrict__ Psum, float* __restrict__ Psq)
{
    int b = blockIdx.y, p0 = blockIdx.x << 8;
    int tid = threadIdx.x;
    int wave = tid >> 6, lane = tid & 63, q = lane >> 4, l15 = lane & 15;
    __shared__ short tile[256 * 64];   // [px 256][ic 64] bf16, icblk xor-swizzled by px&7
    __shared__ float RED[4][64][2];

    floatx4 acc[4][4];
    #pragma unroll
    for (int i = 0; i < 4; ++i)
        #pragma unroll
        for (int mt = 0; mt < 4; ++mt) acc[i][mt] = (floatx4){0.f, 0.f, 0.f, 0.f};

    const float* xb = x + ((long)b << 20) + p0 + tid;
    for (int chunk = 0; chunk < 4; ++chunk) {
        __syncthreads();
        #pragma unroll
        for (int half = 0; half < 2; ++half) {
            float v[32];
            #pragma unroll
            for (int i = 0; i < 32; ++i)
                v[i] = xb[(long)((chunk << 6) + (half << 5) + i) << 12];
            #pragma unroll
            for (int blk = 0; blk < 4; ++blk) {
                int icblk = (half << 2) + blk;
                short8 s;
                #pragma unroll
                for (int e = 0; e < 8; ++e) s[e] = (short)f2bf(v[(blk << 3) + e]);
                int sw = icblk ^ (tid & 7);
                *(short8*)&tile[(tid << 6) + (sw << 3)] = s;
            }
        }
        __syncthreads();
        #pragma unroll
        for (int kq = 0; kq < 2; ++kq) {
            short8 afr[4], bfr[4];
            int kbase = (chunk << 6) + (kq << 5) + (q << 3);
            #pragma unroll
            for (int mt = 0; mt < 4; ++mt)
                afr[mt] = *(const short8*)(wsb + ((mt << 4) + l15) * 256 + kbase);
            #pragma unroll
            for (int i = 0; i < 4; ++i) {
                int px = (((wave << 2) + i) << 4) + l15;
                int sw = ((kq << 2) + q) ^ (px & 7);
                bfr[i] = *(const short8*)&tile[(px << 6) + (sw << 3)];
            }
            #pragma unroll
            for (int i = 0; i < 4; ++i)
                #pragma unroll
                for (int mt = 0; mt < 4; ++mt)
                    acc[i][mt] = __builtin_amdgcn_mfma_f32_16x16x32_bf16(afr[mt], bfr[i], acc[i][mt], 0, 0, 0);
        }
    }
    // GN partials from fp32 acc: value at (px = tile(i)+l15, oc = mt*16 + q*4 + r)
    #pragma unroll
    for (int mt = 0; mt < 4; ++mt)
        #pragma unroll
        for (int r = 0; r < 4; ++r) {
            float sv = 0.f, qv = 0.f;
            #pragma unroll
            for (int i = 0; i < 4; ++i) { float v = acc[i][mt][r]; sv += v; qv += v * v; }
            #pragma unroll
            for (int m = 1; m <= 8; m <<= 1) {
                sv += __shfl_xor(sv, m, 64);
                qv += __shfl_xor(qv, m, 64);
            }
            if (l15 == 0) {
                RED[wave][(mt << 4) + (q << 2) + r][0] = sv;
                RED[wave][(mt << 4) + (q << 2) + r][1] = qv;
            }
        }
    // NHWC fp32 store
    float* ob = s_nhwc + ((long)b << 18) + ((long)p0 << 6);
    #pragma unroll
    for (int i = 0; i < 4; ++i) {
        int px = (((wave << 2) + i) << 4) + l15;
        #pragma unroll
        for (int mt = 0; mt < 4; ++mt)
            *(floatx4*)(ob + (px << 6) + (mt << 4) + (q << 2)) = acc[i][mt];
    }
    __syncthreads();
    if (tid < 64) {
        float S = 0.f, Q = 0.f;
        #pragma unroll
        for (int w = 0; w < 4; ++w) { S += RED[w][tid][0]; Q += RED[w][tid][1]; }
        int idx = (((blockIdx.x << 5) + b) << 6) + tid;
        Psum[idx] = S; Psq[idx] = Q;
    }
}

// ---------------- K_FIN: partials -> per-channel affine (shared by s and y) ----------------
__global__ __launch_bounds__(64) void k_fin(
    const float* __restrict__ Ps, const float* __restrict__ Pq,
    const float* __restrict__ gnw, const float* __restrict__ gnb,
    float* __restrict__ A, float* __restrict__ Bc)
{
    int b = blockIdx.x, c = threadIdx.x;
    float s = 0.f, s2 = 0.f;
    for (int k = 0; k < 16; ++k) {
        int idx = (((k << 5) + b) << 6) + c;
        s += Ps[idx]; s2 += Pq[idx];
    }
    float sp = __shfl_xor(s, 1, 64), qp = __shfl_xor(s2, 1, 64);
    float S = s + sp, Q = s2 + qp;
    float mean = S * (1.f / 8192.f);
    float var  = Q * (1.f / 8192.f) - mean * mean;
    float inv  = rsqrtf(var + EPS);
    float a = gnw[c] * inv;
    A[b * 64 + c] = a;
    Bc[b * 64 + c] = gnb[c] - mean * a;
}

// ---------------- K4: fused GN+ReLU + global corr + depthwise7x7 ----------------
// s NHWC fp32 in, corrT NHWC bf16 out. grid (64 = 8x * 8y tiles, 32 b).
// Block: 8x8 spatial x 64 ch; halo 14x14x64 fp32 in LDS (50 KB).
// GN+ReLU applied at STAGING so that out-of-range padding stays 0 after the
// affine (reference zero-pads relu(GN(s)), not raw s — R5/R6 bug).
__global__ __launch_bounds__(256) void k4_nhwc(
    const float* __restrict__ s_nhwc, const float* __restrict__ A, const float* __restrict__ Bc,
    const float* __restrict__ t_global, const float* __restrict__ t_kernel,
    unsigned short* __restrict__ corrT)
{
    int bx = blockIdx.x & 7, by = blockIdx.x >> 3, b = blockIdx.y;
    int px0 = bx << 3, py0 = by << 3;
    int tid = threadIdx.x, c = tid & 63, slot = tid >> 6;
    __shared__ float H[14 * 14 * 64];   // 50176 B, GN+ReLU'd values (0 in padding)
    const float* sb = s_nhwc + ((long)b << 18);
    int ch4 = tid & 15;                  // constant per thread across staging iters
    float4 a4 = *(const float4*)(A  + b * 64 + (ch4 << 2));
    float4 b4 = *(const float4*)(Bc + b * 64 + (ch4 << 2));
    for (int f4 = tid; f4 < 3136; f4 += 256) {     // 196 cells x 16 float4
        int cell = f4 >> 4;
        int r = cell / 14, c2 = cell - 14 * r;
        int gy = py0 - 3 + r, gx = px0 - 3 + c2;
        float4 v = {0.f, 0.f, 0.f, 0.f};
        if (gy >= 0 && gy < 64 && gx >= 0 && gx < 64) {
            float4 rv = *(const float4*)(sb + (((gy << 6) + gx) << 6) + (ch4 << 2));
            v.x = a4.x * rv.x + b4.x; v.x = v.x > 0.f ? v.x : 0.f;
            v.y = a4.y * rv.y + b4.y; v.y = v.y > 0.f ? v.y : 0.f;
            v.z = a4.z * rv.z + b4.z; v.z = v.z > 0.f ? v.z : 0.f;
            v.w = a4.w * rv.w + b4.w; v.w = v.w > 0.f ? v.w : 0.f;
        }
        *(float4*)&H[(cell << 6) + (ch4 << 2)] = v;
    }
    float tg = t_global[b * 64 + c];
    float kreg[49];
    #pragma unroll
    for (int t = 0; t < 49; ++t) kreg[t] = t_kernel[(b * 64 + c) * 49 + t];
    __syncthreads();
    int oy = slot << 1;    // 2 output rows per slot
    float win[7][8];       // [col-slot][halo rows oy..oy+7]
    #pragma unroll
    for (int kx = 0; kx < 7; ++kx)
        #pragma unroll
        for (int j = 0; j < 8; ++j)
            win[kx][j] = H[(((oy + j) * 14 + kx) << 6) + c];
    unsigned short* ob = corrT + ((long)b << 18);
    #pragma unroll
    for (int ox = 0; ox < 8; ++ox) {
        if (ox > 0) {
            int sl = (ox + 6) % 7;
            #pragma unroll
            for (int j = 0; j < 8; ++j)
                win[sl][j] = H[(((oy + j) * 14 + ox + 6) << 6) + c];
        }
        float a0 = 0.f, a1 = 0.f;
        #pragma unroll
        for (int kx = 0; kx < 7; ++kx) {
            int sl = (ox + kx) % 7;
            #pragma unroll
            for (int ky = 0; ky < 7; ++ky) {
                float kv = kreg[ky * 7 + kx];
                a0 += kv * win[sl][ky];
                a1 += kv * win[sl][ky + 1];
            }
        }
        int cs = (ox + 3) % 7;
        a0 += win[cs][3] * tg;
        a1 += win[cs][4] * tg;
        ob[((((py0 + oy) << 6) + px0 + ox) << 6) + c]     = f2bf(a0);
        ob[((((py0 + oy + 1) << 6) + px0 + ox) << 6) + c] = f2bf(a1);
    }
}

// ---------------- K5: conv3x3 via bf16 MFMA (NHWC in/out) + GN partials ----------------
__global__ __launch_bounds__(256) void k5_mfma(
    const unsigned short* __restrict__ corrT, const unsigned short* __restrict__ wpk,
    unsigned short* __restrict__ y, float* __restrict__ Psum, float* __restrict__ Psq)
{
    int b = blockIdx.y, py0 = blockIdx.x << 2;
    int tid = threadIdx.x;
    int wave = tid >> 6, lane = tid & 63, q = lane >> 4, l15 = lane & 15;
    __shared__ short tile[25344];   // [row 6][col 66][ic 64] bf16, xor-swizzled
    __shared__ float RED[4][64][2];

    for (int u = tid; u < 3168; u += 256) {
        int icblk = u & 7, rc = u >> 3;
        int row = rc / 66, col = rc - 66 * row;
        int py = py0 - 1 + row, px = col - 1;
        short8 v = {0, 0, 0, 0, 0, 0, 0, 0};
        if (py >= 0 && py < 64 && px >= 0 && px < 64)
            v = *(const short8*)(corrT + (((b << 12) + (py << 6) + px) << 6) + (icblk << 3));
        int sw = icblk ^ (col & 7);
        *(short8*)&tile[(rc << 6) + (sw << 3)] = v;
    }
    __syncthreads();

    floatx4 acc[4][4];
    #pragma unroll
    for (int i = 0; i < 4; ++i)
        #pragma unroll
        for (int ot = 0; ot < 4; ++ot) acc[i][ot] = (floatx4){0.f, 0.f, 0.f, 0.f};

    int pt0 = wave << 2;
    int rowb[4], colb[4];
    #pragma unroll
    for (int i = 0; i < 4; ++i) {
        int p = ((pt0 + i) << 4) + l15;
        rowb[i] = p >> 6;
        colb[i] = p & 63;
    }
    #pragma unroll
    for (int c = 0; c < 18; ++c) {
        const int tap = c >> 1, ky = tap / 3, kx = tap % 3, h = c & 1;
        short8 bfr[4], afr[4];
        #pragma unroll
        for (int ot = 0; ot < 4; ++ot)
            bfr[ot] = *(const short8*)(wpk + ((c << 6) + (ot << 4) + l15) * 32 + (q << 3));
        #pragma unroll
        for (int i = 0; i < 4; ++i) {
            int row = rowb[i] + ky, col = colb[i] + kx;
            int sw = ((h << 2) + q) ^ (col & 7);
            afr[i] = *(const short8*)&tile[((row * 66 + col) << 6) + (sw << 3)];
        }
        #pragma unroll
        for (int i = 0; i < 4; ++i)
            #pragma unroll
            for (int ot = 0; ot < 4; ++ot)
                acc[i][ot] = __builtin_amdgcn_mfma_f32_16x16x32_bf16(afr[i], bfr[ot], acc[i][ot], 0, 0, 0);
    }
    // GN partials: px over (i,q,r), oc = ot*16 + l15; reduce over q (lane bits 4,5)
    #pragma unroll
    for (int ot = 0; ot < 4; ++ot) {
        float sv = 0.f, qv = 0.f;
        #pragma unroll
        for (int i = 0; i < 4; ++i)
            #pragma unroll
            for (int r = 0; r < 4; ++r) { float v = acc[i][ot][r]; sv += v; qv += v * v; }
        sv += __shfl_xor(sv, 16, 64); qv += __shfl_xor(qv, 16, 64);
        sv += __shfl_xor(sv, 32, 64); qv += __shfl_xor(qv, 32, 64);
        if (q == 0) { RED[wave][(ot << 4) + l15][0] = sv; RED[wave][(ot << 4) + l15][1] = qv; }
    }
    #pragma unroll
    for (int i = 0; i < 4; ++i) {
        #pragma unroll
        for (int r = 0; r < 4; ++r) {
            int p = ((pt0 + i) << 4) + (q << 2) + r;
            int py = py0 + (p >> 6), pxc = p & 63;
            int base = ((b << 12) + (py << 6) + pxc) << 6;
            #pragma unroll
            for (int ot = 0; ot < 4; ++ot)
                y[base + (ot << 4) + l15] = f2bf(acc[i][ot][r]);
        }
    }
    __syncthreads();
    if (tid < 64) {
        float S = 0.f, Q = 0.f;
        #pragma unroll
        for (int w = 0; w < 4; ++w) { S += RED[w][tid][0]; Q += RED[w][tid][1]; }
        int idx = (((blockIdx.x << 5) + b) << 6) + tid;
        Psum[idx] = S; Psq[idx] = Q;
    }
}

// ---------------- K6: epilogue on NHWC bf16 y ----------------
__global__ __launch_bounds__(256) void k6_nhwc(
    const unsigned short* __restrict__ y, const float* __restrict__ A, const float* __restrict__ Bc,
    const float* __restrict__ w2, const float* __restrict__ b2, float* __restrict__ out)
{
    int b = blockIdx.y;
    int px0 = blockIdx.x << 9;
    int tid = threadIdx.x, wave = tid >> 6, lane = tid & 63;
    int ocp = lane & 31, ph = lane >> 5;
    int c0 = 2 * ocp;
    float a0 = A[b * 64 + c0],     b0 = Bc[b * 64 + c0],     w20 = w2[c0];
    float a1 = A[b * 64 + c0 + 1], b1 = Bc[b * 64 + c0 + 1], w21 = w2[c0 + 1];
    float bias = b2[0];
    const unsigned* yp = (const unsigned*)y;
    for (int i = 0; i < 64; ++i) {
        int px = px0 + (i << 3) + (wave << 1) + ph;
        unsigned u = yp[(((b << 12) + px) << 5) + ocp];
        float f0 = bf2f((unsigned short)(u & 0xFFFF));
        float f1 = bf2f((unsigned short)(u >> 16));
        float v0 = a0 * f0 + b0; v0 = v0 > 0.f ? v0 : 0.f;
        float v1 = a1 * f1 + b1; v1 = v1 > 0.f ? v1 : 0.f;
        float val = w20 * v0 + w21 * v1;
        #pragma unroll
        for (int m = 16; m >= 1; m >>= 1) val += __shfl_xor(val, m, 64);
        if (ocp == 0) out[(b << 12) + px] = val + bias;
    }
}

extern "C" void kernel_launch(void* const* d_in, const int* in_sizes, int n_in,
                              void* d_out, int out_size, void* d_ws, size_t ws_size,
                              hipStream_t stream)
{
    const float* tmpl   = (const float*)d_in[0];
    const float* search = (const float*)d_in[1];
    const float* w_t    = (const float*)d_in[2];
    const float* gn_t_w = (const float*)d_in[3];
    const float* gn_t_b = (const float*)d_in[4];
    const float* w_s    = (const float*)d_in[5];
    const float* gn_s_w = (const float*)d_in[6];
    const float* gn_s_b = (const float*)d_in[7];
    const float* w_p1   = (const float*)d_in[8];
    const float* gn_p_w = (const float*)d_in[9];
    const float* gn_p_b = (const float*)d_in[10];
    const float* w_p2   = (const float*)d_in[11];
    const float* b_p2   = (const float*)d_in[12];
    float* out = (float*)d_out;
    float* ws  = (float*)d_ws;

    float* TG   = ws;                        // 2048
    float* TK   = ws + 2048;                 // 100352
    float* AS   = ws + 102400;               // 2048
    float* BS   = ws + 104448;               // 2048
    float* AY   = ws + 106496;               // 2048
    float* BY   = ws + 108544;               // 2048
    float* PS   = ws + 110592;               // 32768 (partials, reused s then y)
    float* PQ   = ws + 143360;               // 32768
    unsigned short* WPK = (unsigned short*)(ws + 176128);   // 36864 bf16
    unsigned short* WSB = (unsigned short*)(ws + 194560);   // 16384 bf16
    float* SN = ws + 202752;                                            // 8388608 fp32 (32 MB)
    unsigned short* CORRT = (unsigned short*)(ws + 202752 + 8388608);   // 16 MB
    unsigned short* YRAW  = (unsigned short*)(ws + 202752 + 12582912);  // 16 MB

    k_w2<<<64, 256, 0, stream>>>(w_s, WSB);
    k_w<<<144, 256, 0, stream>>>(w_p1, WPK);
    k1_template<<<128, 256, 0, stream>>>(tmpl, w_t, gn_t_w, gn_t_b, TG, TK);
    k2_mfma<<<dim3(16, 32), 256, 0, stream>>>(search, WSB, SN, PS, PQ);
    k_fin<<<32, 64, 0, stream>>>(PS, PQ, gn_s_w, gn_s_b, AS, BS);
    k4_nhwc<<<dim3(64, 32), 256, 0, stream>>>(SN, AS, BS, TG, TK, CORRT);
    k5_mfma<<<dim3(16, 32), 256, 0, stream>>>(CORRT, WPK, YRAW, PS, PQ);
    k_fin<<<32, 64, 0, stream>>>(PS, PQ, gn_p_w, gn_p_b, AY, BY);
    k6_nhwc<<<dim3(8, 32), 256, 0, stream>>>(YRAW, AY, BY, w_p2, b_p2, out);
}